// Round 4
// baseline (462.578 us; speedup 1.0000x reference)
//
#include <hip/hip_runtime.h>
#include <hip/hip_bf16.h>
#include <cstdint>
#include <cstddef>

// Problem constants
#define E_TOT   1048576
#define BGR     64
#define NN      1024
#define DD      128
#define HID     256
#define NH      4
#define NSEG    65536
#define KDIM    96           // x in bf16; ctxt (globs/cndts) folded separately
#define NKCH    12           // KDIM/8 chunks
#define BM      128          // edges per M-tile (8 waves x 16 edges)
#define NTILES  (E_TOT/BM)   // 8192
#define GRIDM   512          // persistent blocks (2/CU)
#define TPB     (NTILES/GRIDM) // 16 tiles per block

typedef __attribute__((ext_vector_type(8))) short s16x8;   // 8 bf16
typedef __attribute__((ext_vector_type(4))) float f32x4;

static __device__ __forceinline__ unsigned short f2bf_rn(float f) {
    unsigned u = __float_as_uint(f);
    unsigned r = u + 0x7FFF + ((u >> 16) & 1);   // round-to-nearest-even
    return (unsigned short)(r >> 16);
}

// ---------------------------------------------------------------------------
// Prep A: Wg [12 kchunk][256 hidden][8] bf16 = bf16(W1[0:96])  (MFMA A layout)
// ---------------------------------------------------------------------------
__global__ __launch_bounds__(256)
void k_prep_w(const float* __restrict__ W1, short* __restrict__ Wg) {
    int idx = blockIdx.x * 256 + threadIdx.x;        // < 12*256*8 = 24576
    int kchunk = idx >> 11;
    int n      = (idx >> 3) & 255;
    int j      = idx & 7;
    int k      = kchunk * 8 + j;                     // 0..95
    Wg[idx] = (short)f2bf_rn(W1[k * 256 + n]);
}

// ---------------------------------------------------------------------------
// Prep B: ctxtc[64][256] = b1 + globs[b]·W1[96:104] + cndts[b]·W1[104:112]
// ---------------------------------------------------------------------------
__global__ __launch_bounds__(256)
void k_prep_ctx(const float* __restrict__ W1, const float* __restrict__ b1,
                const float* __restrict__ globs, const float* __restrict__ cndts,
                float* __restrict__ ctxtc) {
    int b = blockIdx.x, j = threadIdx.x;
    float s = b1[j];
    #pragma unroll
    for (int g = 0; g < 8; ++g) s = fmaf(globs[b * 8 + g], W1[(96 + g) * 256 + j], s);
    #pragma unroll
    for (int c = 0; c < 8; ++c) s = fmaf(cndts[b * 8 + c], W1[(104 + c) * 256 + j], s);
    ctxtc[b * 256 + j] = s;
}

// ---------------------------------------------------------------------------
// Count edges per segment
// ---------------------------------------------------------------------------
__global__ __launch_bounds__(256)
void k_count(const int* __restrict__ batch_idx, const int* __restrict__ recv_idx,
             int* __restrict__ counts)
{
    int e = blockIdx.x * 256 + threadIdx.x;
    atomicAdd(&counts[batch_idx[e] * NN + recv_idx[e]], 1);
}

// ---------------------------------------------------------------------------
// Parallel exclusive scan of counts[65536]: 3 small kernels
// ---------------------------------------------------------------------------
__global__ __launch_bounds__(256)
void k_scan1(const int* __restrict__ counts, int* __restrict__ tmp_excl,
             int* __restrict__ blocksums)
{
    __shared__ int sh[256];
    const int t = threadIdx.x;
    const int gid = blockIdx.x * 256 + t;
    int c = counts[gid];
    sh[t] = c;
    __syncthreads();
    int v = c;
    for (int off = 1; off < 256; off <<= 1) {
        int u = (t >= off) ? sh[t - off] : 0;
        __syncthreads();
        v += u; sh[t] = v;
        __syncthreads();
    }
    tmp_excl[gid] = v - c;
    if (t == 255) blocksums[blockIdx.x] = v;
}

__global__ __launch_bounds__(256)
void k_scan2(int* __restrict__ blocksums)
{
    __shared__ int sh[256];
    const int t = threadIdx.x;
    int c = blocksums[t];
    sh[t] = c;
    __syncthreads();
    int v = c;
    for (int off = 1; off < 256; off <<= 1) {
        int u = (t >= off) ? sh[t - off] : 0;
        __syncthreads();
        v += u; sh[t] = v;
        __syncthreads();
    }
    blocksums[t] = v - c;
}

__global__ __launch_bounds__(256)
void k_scan3(const int* __restrict__ tmp_excl, const int* __restrict__ blocksums,
             int* __restrict__ offsets, int* __restrict__ cursor)
{
    const int gid = blockIdx.x * 256 + threadIdx.x;
    int v = tmp_excl[gid] + blocksums[blockIdx.x];
    offsets[gid] = v;
    cursor[gid]  = v;
}

// ---------------------------------------------------------------------------
// Scatter edge ids into per-segment lists (counting sort)
// ---------------------------------------------------------------------------
__global__ __launch_bounds__(256)
void k_scatter(const int* __restrict__ batch_idx, const int* __restrict__ recv_idx,
               int* __restrict__ cursor, int* __restrict__ elist)
{
    int e   = blockIdx.x * 256 + threadIdx.x;
    int seg = batch_idx[e] * NN + recv_idx[e];
    int pos = atomicAdd(&cursor[seg], 1);
    elist[pos] = e;
}

// ---------------------------------------------------------------------------
// Main fused MFMA kernel (K=96 bf16). 512 persistent blocks x 512 threads
// (2 blocks/CU, 76KB LDS each). Each wave owns 16 edges x all 256 hidden:
// layer-2 logit resolves in-wave via 2 shfl_xor — no cross-wave LDS reduce.
// Single Xl buffer, 2 barriers/tile; T14 early global loads for tile t+1.
// ---------------------------------------------------------------------------
__global__ __launch_bounds__(512, 4)
void k_mlp_mfma(const float* __restrict__ pooled, const float* __restrict__ edges,
                const short* __restrict__ Wg,     const float* __restrict__ ctxtc,
                const float* __restrict__ W2,
                const int* __restrict__ batch_idx, const int* __restrict__ recv_idx,
                float* __restrict__ ex_out, float* __restrict__ denom)
{
    __shared__ short Wl[NKCH * 256 * 8];        // 49152 B [kchunk][hidden][8]
    __shared__ short Xl[NKCH * 128 * 8];        // 24576 B [kchunk][edge][8]
    __shared__ float sW2[256 * 4];              //  4096 B

    const int tid  = threadIdx.x;
    const int lane = tid & 63;
    const int wid  = tid >> 6;          // wave id 0..7 -> edges wid*16..+15
    const int la   = lane & 15;
    const int g    = lane >> 4;         // 0..3 (k-chunk within ks / acc row grp)

    // ---- prologue: W (layout prebuilt) + W2 into LDS ----
    {
        const float4* src = reinterpret_cast<const float4*>(Wg);
        float4* dst = reinterpret_cast<float4*>(Wl);
        #pragma unroll
        for (int i = 0; i < 6; ++i) dst[i * 512 + tid] = src[i * 512 + tid];
        if (tid < 256)
            *reinterpret_cast<float4*>(&sW2[tid * 4]) =
                reinterpret_cast<const float4*>(W2)[tid];
    }

    const int tile0 = blockIdx.x * TPB;
    const int tend  = tile0 + TPB;

    // staging role: edge = tid>>2 (0..127), quarter sq = tid&3 (24 x-elems)
    const int se_loc = tid >> 2;
    const int sq     = tid & 3;

    // ---- stage tile0 into Xl ----
    {
        const int eg = tile0 * BM + se_loc;
        #pragma unroll
        for (int c2 = 0; c2 < 3; ++c2) {
            int elem = sq * 24 + c2 * 8;
            const float* p0 = (elem < 32) ? (pooled + (size_t)eg * 32 + elem)
                                          : (edges + (size_t)eg * 64 + (elem - 32));
            float4 v0 = *reinterpret_cast<const float4*>(p0);
            elem += 4;
            const float* p1 = (elem < 32) ? (pooled + (size_t)eg * 32 + elem)
                                          : (edges + (size_t)eg * 64 + (elem - 32));
            float4 v1 = *reinterpret_cast<const float4*>(p1);
            float vals[8] = { v0.x, v0.y, v0.z, v0.w, v1.x, v1.y, v1.z, v1.w };
            s16x8 hv;
            #pragma unroll
            for (int i = 0; i < 8; ++i) hv[i] = (short)f2bf_rn(vals[i]);
            int kch = sq * 3 + c2;
            *reinterpret_cast<s16x8*>(&Xl[(kch * 128 + se_loc) * 8]) = hv;
        }
    }
    __syncthreads();

    for (int t = tile0; t < tend; ++t) {
        const int e0 = t * BM;
        const bool has_next = (t + 1 < tend);

        // ---- T14: issue next tile's global loads early ----
        float4 sv[6];
        if (has_next) {
            const int eg = (t + 1) * BM + se_loc;
            #pragma unroll
            for (int c = 0; c < 6; ++c) {
                int elem = sq * 24 + c * 4;
                const float* p = (elem < 32) ? (pooled + (size_t)eg * 32 + elem)
                                             : (edges + (size_t)eg * 64 + (elem - 32));
                sv[c] = *reinterpret_cast<const float4*>(p);
            }
        }

        // ---- K-loop: 3 ks x 16 hf MFMA (wave: 16 edges x 256 hidden) ----
        f32x4 acc[16];
        #pragma unroll
        for (int i = 0; i < 16; ++i) acc[i] = (f32x4){0.f, 0.f, 0.f, 0.f};

        #pragma unroll
        for (int ks = 0; ks < 3; ++ks) {
            const s16x8 xf = *reinterpret_cast<const s16x8*>(
                &Xl[((ks * 4 + g) * 128 + wid * 16 + la) * 8]);
            const short* wrow = &Wl[((ks * 4 + g) * 256 + la) * 8];
            #pragma unroll
            for (int hf = 0; hf < 16; ++hf) {
                s16x8 wf = *reinterpret_cast<const s16x8*>(wrow + hf * 128);
                acc[hf] = __builtin_amdgcn_mfma_f32_16x16x32_bf16(wf, xf, acc[hf], 0, 0, 0);
            }
        }

        __syncthreads();   // barrier1: all reads of Xl(t) complete

        // ---- convert + write next tile into Xl (epilogue below hides it) ----
        if (has_next) {
            #pragma unroll
            for (int c2 = 0; c2 < 3; ++c2) {
                float vals[8] = { sv[2*c2].x, sv[2*c2].y, sv[2*c2].z, sv[2*c2].w,
                                  sv[2*c2+1].x, sv[2*c2+1].y, sv[2*c2+1].z, sv[2*c2+1].w };
                s16x8 hv;
                #pragma unroll
                for (int i = 0; i < 8; ++i) hv[i] = (short)f2bf_rn(vals[i]);
                int kch = sq * 3 + c2;
                *reinterpret_cast<s16x8*>(&Xl[(kch * 128 + se_loc) * 8]) = hv;
            }
        }

        // ---- epilogue: +ctxt, leaky, layer-2, in-wave reduce, exp, atomics ----
        {
            const int eg = e0 + wid * 16 + la;       // this lane's edge
            const int b  = batch_idx[eg];
            const float* cxb = &ctxtc[(size_t)b * 256 + g * 4];
            float pl0 = 0.f, pl1 = 0.f, pl2 = 0.f, pl3 = 0.f;
            #pragma unroll
            for (int hf = 0; hf < 16; ++hf) {
                const float4 cx = *reinterpret_cast<const float4*>(cxb + hf * 16);
                const float cxa[4] = {cx.x, cx.y, cx.z, cx.w};
                #pragma unroll
                for (int r = 0; r < 4; ++r) {
                    float s = acc[hf][r] + cxa[r];
                    float h = fmaxf(s, 0.1f * s);    // leaky_relu(0.1)
                    const float4 w2 = *reinterpret_cast<const float4*>(
                        &sW2[(hf * 16 + g * 4 + r) * 4]);
                    pl0 = fmaf(h, w2.x, pl0);
                    pl1 = fmaf(h, w2.y, pl1);
                    pl2 = fmaf(h, w2.z, pl2);
                    pl3 = fmaf(h, w2.w, pl3);
                }
            }
            // sum the 4 g-groups (lanes la, la+16, la+32, la+48 share an edge)
            pl0 += __shfl_xor(pl0, 16); pl0 += __shfl_xor(pl0, 32);
            pl1 += __shfl_xor(pl1, 16); pl1 += __shfl_xor(pl1, 32);
            pl2 += __shfl_xor(pl2, 16); pl2 += __shfl_xor(pl2, 32);
            pl3 += __shfl_xor(pl3, 16); pl3 += __shfl_xor(pl3, 32);
            float myl = (g == 0) ? pl0 : (g == 1) ? pl1 : (g == 2) ? pl2 : pl3;
            float exv = __expf(myl);                 // lane g handles head g
            ex_out[(size_t)eg * 4 + g] = exv;
            const int seg = b * NN + recv_idx[eg];
            atomicAdd(&denom[seg * 4 + g], exv);
        }

        __syncthreads();   // barrier2: Xl(t+1) ready for everyone
    }
}

// ---------------------------------------------------------------------------
// K4: one wave per segment; lane owns 2 of 128 dims; head = lane>>4.
// 4-way unrolled so 4 independent new_edges rows are in flight.
// ---------------------------------------------------------------------------
__global__ __launch_bounds__(256)
void k_gather(const float* __restrict__ new_edges, const float* __restrict__ ex,
              const float* __restrict__ denom, const int* __restrict__ offsets,
              const int* __restrict__ counts, const int* __restrict__ elist,
              float* __restrict__ out)
{
    const int gid  = blockIdx.x * 256 + threadIdx.x;
    const int seg  = gid >> 6;
    const int lane = threadIdx.x & 63;
    if (seg >= NSEG) return;

    const int start = offsets[seg];
    const int cnt   = counts[seg];
    const int h     = lane >> 4;
    const int doff  = lane * 2;

    float a0 = 0.f, a1 = 0.f;
    int i = 0;
    for (; i + 4 <= cnt; i += 4) {
        const int el0 = elist[start + i + 0];
        const int el1 = elist[start + i + 1];
        const int el2 = elist[start + i + 2];
        const int el3 = elist[start + i + 3];
        const float w0 = ex[(size_t)el0 * 4 + h];
        const float w1 = ex[(size_t)el1 * 4 + h];
        const float w2 = ex[(size_t)el2 * 4 + h];
        const float w3 = ex[(size_t)el3 * 4 + h];
        const float2 n0 = *reinterpret_cast<const float2*>(new_edges + (size_t)el0 * DD + doff);
        const float2 n1 = *reinterpret_cast<const float2*>(new_edges + (size_t)el1 * DD + doff);
        const float2 n2 = *reinterpret_cast<const float2*>(new_edges + (size_t)el2 * DD + doff);
        const float2 n3 = *reinterpret_cast<const float2*>(new_edges + (size_t)el3 * DD + doff);
        a0 = fmaf(n0.x, w0, a0); a1 = fmaf(n0.y, w0, a1);
        a0 = fmaf(n1.x, w1, a0); a1 = fmaf(n1.y, w1, a1);
        a0 = fmaf(n2.x, w2, a0); a1 = fmaf(n2.y, w2, a1);
        a0 = fmaf(n3.x, w3, a0); a1 = fmaf(n3.y, w3, a1);
    }
    for (; i < cnt; ++i) {
        const int el = elist[start + i];
        const float w = ex[(size_t)el * 4 + h];
        const float2 n = *reinterpret_cast<const float2*>(new_edges + (size_t)el * DD + doff);
        a0 = fmaf(n.x, w, a0); a1 = fmaf(n.y, w, a1);
    }
    const float scale = (cnt > 0) ? 1.0f / denom[seg * 4 + h] : 0.0f;
    float2 r; r.x = a0 * scale; r.y = a1 * scale;
    *reinterpret_cast<float2*>(out + (size_t)seg * DD + doff) = r;
}

// ---------------------------------------------------------------------------
extern "C" void kernel_launch(void* const* d_in, const int* in_sizes, int n_in,
                              void* d_out, int out_size, void* d_ws, size_t ws_size,
                              hipStream_t stream)
{
    const float* new_edges = (const float*)d_in[0];
    const float* edges     = (const float*)d_in[1];
    const float* pooled    = (const float*)d_in[2];
    const float* globs     = (const float*)d_in[3];
    const float* cndts     = (const float*)d_in[4];
    const float* W1        = (const float*)d_in[5];
    const float* b1        = (const float*)d_in[6];
    const float* W2        = (const float*)d_in[7];
    // b2 (d_in[8]) cancels in the per-head softmax — intentionally unused
    const int*   batch_idx = (const int*)d_in[9];
    const int*   recv_idx  = (const int*)d_in[10];
    float* out = (float*)d_out;

    char* ws = (char*)d_ws;
    float* ex       = (float*)(ws);                              // 16 MB
    float* denom    = (float*)(ws + (size_t)16 * 1024 * 1024);   // 1 MB
    char*  base17   = ws + (size_t)17 * 1024 * 1024;
    int*   counts   = (int*)(base17);                            // 256 KB
    int*   offs     = (int*)(base17 + 1 * 262144);
    int*   cursor   = (int*)(base17 + 2 * 262144);
    int*   tmp_excl = (int*)(base17 + 3 * 262144);
    int*   bsums    = (int*)(base17 + 4 * 262144);               // 1 KB
    int*   elist    = (int*)(ws + (size_t)18 * 1024 * 1024);     // 4 MB
    short* Wg       = (short*)(ws + (size_t)22 * 1024 * 1024);   // 49,152 B
    float* ctxtc    = (float*)(ws + (size_t)22 * 1024 * 1024 + 65536); // 64 KB

    // denom (1 MB) + counts (256 KB) contiguous: one memset
    hipMemsetAsync(denom, 0,
                   (size_t)NSEG * NH * sizeof(float) + (size_t)NSEG * sizeof(int),
                   stream);

    // index-only chain (independent of MLP)
    k_count<<<E_TOT / 256, 256, 0, stream>>>(batch_idx, recv_idx, counts);
    k_scan1<<<NSEG / 256, 256, 0, stream>>>(counts, tmp_excl, bsums);
    k_scan2<<<1, 256, 0, stream>>>(bsums);
    k_scan3<<<NSEG / 256, 256, 0, stream>>>(tmp_excl, bsums, offs, cursor);
    k_scatter<<<E_TOT / 256, 256, 0, stream>>>(batch_idx, recv_idx, cursor, elist);

    // MLP chain
    k_prep_w<<<96, 256, 0, stream>>>(W1, Wg);
    k_prep_ctx<<<64, 256, 0, stream>>>(W1, b1, globs, cndts, ctxtc);
    k_mlp_mfma<<<GRIDM, 512, 0, stream>>>(pooled, edges, Wg, ctxtc, W2,
                                          batch_idx, recv_idx, ex, denom);

    // final weighted pool
    k_gather<<<(NSEG * 64) / 256, 256, 0, stream>>>(new_edges, ex, denom,
                                                    offs, counts, elist, out);
}